// Round 1
// baseline (8183.414 us; speedup 1.0000x reference)
//
#include <hip/hip_runtime.h>
#include <math.h>

#define Bsz 16
#define Tsz 1000
#define Nsz 100
#define ENC 512
#define VOCAB 10025
#define EMB 640
#define HID 1024
#define ATT 1024
#define KX (EMB + ENC)          // 1152
#define KRO (HID + EMB + ENC)   // 2176

__device__ __forceinline__ float4 ld4(const float* p) { return *reinterpret_cast<const float4*>(p); }
__device__ __forceinline__ float dot4(float4 a, float4 b) { return a.x*b.x + a.y*b.y + a.z*b.z + a.w*b.w; }
__device__ __forceinline__ float sigmoidf_(float x) { return 1.f / (1.f + __expf(-x)); }
__device__ __forceinline__ float ftanh_(float x) {
    x = fminf(15.f, fmaxf(-15.f, x));
    float e = __expf(2.f * x);
    return (e - 1.f) / (e + 1.f);
}

// ---------------- init: zero accum ----------------
__global__ __launch_bounds__(256) void k_init(float* accum) {
    int i = blockIdx.x * 256 + threadIdx.x;
    if (i < Bsz * Tsz) accum[i] = 0.f;
}

// ---------------- shifted embedding into roA[:, HID:HID+EMB] ----------------
__global__ __launch_bounds__(256) void k_embed(const int* __restrict__ labels,
                                               const float* __restrict__ table,
                                               float* __restrict__ roA) {
    int idx = blockIdx.x * 256 + threadIdx.x;
    if (idx >= Bsz * Nsz * EMB) return;
    int e = idx % EMB;
    int bn = idx / EMB;
    int n = bn % Nsz, b = bn / Nsz;
    float v = 0.f;
    if (n > 0) {
        int lab = labels[b * Nsz + n - 1];
        v = table[(size_t)lab * EMB + e];
    }
    roA[(size_t)bn * KRO + HID + e] = v;
}

// ---------------- generic fp32 NT GEMM: C = A[M,K] @ W[Nc,K]^T + bias ----------------
#define BM 64
#define BN 64
#define BK 16
template <int MAXOUT>
__global__ __launch_bounds__(256) void sgemm_nt(const float* __restrict__ A,
                                                const float* __restrict__ W,
                                                const float* __restrict__ bias,
                                                float* __restrict__ C,
                                                int M, int Nc, int K, int ldC) {
    __shared__ __align__(16) float As[BK][BM + 4];
    __shared__ __align__(16) float Ws[BK][BN + 4];
    int m0 = blockIdx.y * BM, n0 = blockIdx.x * BN;
    int tid = threadIdx.x;
    int tx = tid & 15, ty = tid >> 4;
    int lr = tid >> 2;          // 0..63
    int lk = (tid & 3) * 4;     // 0,4,8,12
    float acc[4][4] = {};
    for (int k0 = 0; k0 < K; k0 += BK) {
        {
            int m = m0 + lr;
            float4 v = (m < M) ? ld4(&A[(size_t)m * K + k0 + lk]) : float4{0.f, 0.f, 0.f, 0.f};
            As[lk + 0][lr] = v.x; As[lk + 1][lr] = v.y; As[lk + 2][lr] = v.z; As[lk + 3][lr] = v.w;
        }
        {
            int n = n0 + lr;
            float4 v = (n < Nc) ? ld4(&W[(size_t)n * K + k0 + lk]) : float4{0.f, 0.f, 0.f, 0.f};
            Ws[lk + 0][lr] = v.x; Ws[lk + 1][lr] = v.y; Ws[lk + 2][lr] = v.z; Ws[lk + 3][lr] = v.w;
        }
        __syncthreads();
#pragma unroll
        for (int k = 0; k < BK; k++) {
            float4 a = *reinterpret_cast<const float4*>(&As[k][ty * 4]);
            float4 w = *reinterpret_cast<const float4*>(&Ws[k][tx * 4]);
            acc[0][0] += a.x * w.x; acc[0][1] += a.x * w.y; acc[0][2] += a.x * w.z; acc[0][3] += a.x * w.w;
            acc[1][0] += a.y * w.x; acc[1][1] += a.y * w.y; acc[1][2] += a.y * w.z; acc[1][3] += a.y * w.w;
            acc[2][0] += a.z * w.x; acc[2][1] += a.z * w.y; acc[2][2] += a.z * w.z; acc[2][3] += a.z * w.w;
            acc[3][0] += a.w * w.x; acc[3][1] += a.w * w.y; acc[3][2] += a.w * w.z; acc[3][3] += a.w * w.w;
        }
        __syncthreads();
    }
#pragma unroll
    for (int i = 0; i < 4; i++) {
        int m = m0 + ty * 4 + i;
        if (m >= M) continue;
        if (MAXOUT) {
#pragma unroll
            for (int j = 0; j < 2; j++) {
                int n = n0 + tx * 4 + 2 * j;
                float v0 = acc[i][2 * j] + bias[n];
                float v1 = acc[i][2 * j + 1] + bias[n + 1];
                C[(size_t)m * ldC + n / 2] = fmaxf(v0, v1);
            }
        } else {
#pragma unroll
            for (int j = 0; j < 4; j++) {
                int n = n0 + tx * 4 + j;
                if (n < Nc) C[(size_t)m * ldC + n] = acc[i][j] + bias[n];
            }
        }
    }
}

// ---------------- inv_fertility: sigmoid(enc @ W_fert), one wave per (b,t) ----------------
__global__ __launch_bounds__(256) void k_ifert(const float* __restrict__ enc,
                                               const float* __restrict__ Wfert,
                                               float* __restrict__ ifert) {
    int wv = (blockIdx.x * 256 + threadIdx.x) >> 6;
    int lane = threadIdx.x & 63;
    if (wv >= Bsz * Tsz) return;
    const float* row = enc + (size_t)wv * ENC;
    float s = 0.f;
    for (int k = lane * 4; k < ENC; k += 256) s += dot4(ld4(row + k), ld4(Wfert + k));
    for (int o = 32; o; o >>= 1) s += __shfl_xor(s, o, 64);
    if (lane == 0) ifert[wv] = 1.f / (1.f + __expf(-s));
}

// ---------------- gates + LSTM cell: one wave per (hid unit j, batch-half) ----------------
__global__ __launch_bounds__(256) void k_gates(float* __restrict__ roA, float* __restrict__ cbuf,
                                               const float* __restrict__ Wih, const float* __restrict__ Whh,
                                               const float* __restrict__ bih, const float* __restrict__ bhh,
                                               int t) {
    int wv = (blockIdx.x * 256 + threadIdx.x) >> 6;  // 0..2047
    int lane = threadIdx.x & 63;
    int j = wv >> 1;
    int b0 = (wv & 1) << 3;
    float acc[4][8];
#pragma unroll
    for (int g = 0; g < 4; g++)
#pragma unroll
        for (int bb = 0; bb < 8; bb++) acc[g][bb] = 0.f;

    const float* wi0 = Wih + (size_t)(0 * HID + j) * KX;
    const float* wi1 = Wih + (size_t)(1 * HID + j) * KX;
    const float* wi2 = Wih + (size_t)(2 * HID + j) * KX;
    const float* wi3 = Wih + (size_t)(3 * HID + j) * KX;
    const float* wh0 = Whh + (size_t)(0 * HID + j) * HID;
    const float* wh1 = Whh + (size_t)(1 * HID + j) * HID;
    const float* wh2 = Whh + (size_t)(2 * HID + j) * HID;
    const float* wh3 = Whh + (size_t)(3 * HID + j) * HID;
    const float* xrow[8];
    const float* prow[8];
#pragma unroll
    for (int bb = 0; bb < 8; bb++) {
        xrow[bb] = roA + (size_t)((b0 + bb) * Nsz + t) * KRO;
        prow[bb] = roA + (size_t)((b0 + bb) * Nsz + (t - 1)) * KRO;
    }
    // x-part 1: embedding (W_ih cols 0..639)
    for (int k = lane * 4; k < EMB; k += 256) {
        float4 w0 = ld4(wi0 + k), w1 = ld4(wi1 + k), w2 = ld4(wi2 + k), w3 = ld4(wi3 + k);
#pragma unroll
        for (int bb = 0; bb < 8; bb++) {
            float4 x = ld4(xrow[bb] + HID + k);
            acc[0][bb] += dot4(w0, x); acc[1][bb] += dot4(w1, x);
            acc[2][bb] += dot4(w2, x); acc[3][bb] += dot4(w3, x);
        }
    }
    if (t > 0) {
        // x-part 2: prev attention context (W_ih cols 640..1151)
        for (int k = lane * 4; k < ENC; k += 256) {
            float4 w0 = ld4(wi0 + EMB + k), w1 = ld4(wi1 + EMB + k), w2 = ld4(wi2 + EMB + k), w3 = ld4(wi3 + EMB + k);
#pragma unroll
            for (int bb = 0; bb < 8; bb++) {
                float4 x = ld4(prow[bb] + HID + EMB + k);
                acc[0][bb] += dot4(w0, x); acc[1][bb] += dot4(w1, x);
                acc[2][bb] += dot4(w2, x); acc[3][bb] += dot4(w3, x);
            }
        }
        // h-part
        for (int k = lane * 4; k < HID; k += 256) {
            float4 w0 = ld4(wh0 + k), w1 = ld4(wh1 + k), w2 = ld4(wh2 + k), w3 = ld4(wh3 + k);
#pragma unroll
            for (int bb = 0; bb < 8; bb++) {
                float4 x = ld4(prow[bb] + k);
                acc[0][bb] += dot4(w0, x); acc[1][bb] += dot4(w1, x);
                acc[2][bb] += dot4(w2, x); acc[3][bb] += dot4(w3, x);
            }
        }
    }
#pragma unroll
    for (int g = 0; g < 4; g++)
#pragma unroll
        for (int bb = 0; bb < 8; bb++) {
            float v = acc[g][bb];
            for (int o = 32; o; o >>= 1) v += __shfl_xor(v, o, 64);
            acc[g][bb] = v;
        }
    if (lane < 8) {
        int b = b0 + lane;
        float gi = acc[0][lane] + bih[j] + bhh[j];
        float gf = acc[1][lane] + bih[HID + j] + bhh[HID + j];
        float gg = acc[2][lane] + bih[2 * HID + j] + bhh[2 * HID + j];
        float go = acc[3][lane] + bih[3 * HID + j] + bhh[3 * HID + j];
        float cold = (t > 0) ? cbuf[b * HID + j] : 0.f;
        float cn = sigmoidf_(gf) * cold + sigmoidf_(gi) * ftanh_(gg);
        float hn = sigmoidf_(go) * ftanh_(cn);
        cbuf[b * HID + j] = cn;
        roA[(size_t)(b * Nsz + t) * KRO + j] = hn;
    }
}

// ---------------- s_t = h_new @ W_s^T : one wave per attention unit a ----------------
__global__ __launch_bounds__(256) void k_s(const float* __restrict__ roA, const float* __restrict__ Wsm,
                                           float* __restrict__ st, int t) {
    int wv = (blockIdx.x * 256 + threadIdx.x) >> 6;  // 0..1023 = a
    int lane = threadIdx.x & 63;
    float acc[16];
#pragma unroll
    for (int b = 0; b < 16; b++) acc[b] = 0.f;
    const float* wr = Wsm + (size_t)wv * HID;
    const float* hrow[16];
#pragma unroll
    for (int b = 0; b < 16; b++) hrow[b] = roA + (size_t)(b * Nsz + t) * KRO;
    for (int k = lane * 4; k < HID; k += 256) {
        float4 w = ld4(wr + k);
#pragma unroll
        for (int b = 0; b < 16; b++) acc[b] += dot4(w, ld4(hrow[b] + k));
    }
#pragma unroll
    for (int b = 0; b < 16; b++) {
        float v = acc[b];
        for (int o = 32; o; o >>= 1) v += __shfl_xor(v, o, 64);
        acc[b] = v;
    }
    if (lane < 16) st[lane * ATT + wv] = acc[lane];
}

// ---------------- attention energies: one wave per (b,t) ----------------
__global__ __launch_bounds__(256) void k_energy(const float* __restrict__ encctx,
                                                const float* __restrict__ st,
                                                const float* __restrict__ Wfb,
                                                const float* __restrict__ vatt,
                                                const float* __restrict__ accum,
                                                const int* __restrict__ seqlen,
                                                float* __restrict__ enw) {
    int wv = (blockIdx.x * 256 + threadIdx.x) >> 6;  // 0..15999
    int lane = threadIdx.x & 63;
    int b = wv / Tsz, t = wv - b * Tsz;
    if (t >= seqlen[b]) {
        if (lane == 0) enw[wv] = -INFINITY;
        return;
    }
    float ac = accum[wv];
    const float* ec = encctx + (size_t)wv * ATT;
    const float* sr = st + b * ATT;
    float e = 0.f;
    for (int k = lane * 4; k < ATT; k += 256) {
        float4 c4 = ld4(ec + k), s4 = ld4(sr + k), f4 = ld4(Wfb + k), v4 = ld4(vatt + k);
        e += ftanh_(c4.x + s4.x + ac * f4.x) * v4.x;
        e += ftanh_(c4.y + s4.y + ac * f4.y) * v4.y;
        e += ftanh_(c4.z + s4.z + ac * f4.z) * v4.z;
        e += ftanh_(c4.w + s4.w + ac * f4.w) * v4.w;
    }
    for (int o = 32; o; o >>= 1) e += __shfl_xor(e, o, 64);
    if (lane == 0) enw[wv] = e;
}

// ---------------- softmax + accum update + zero ctx slot: one block per b ----------------
__global__ __launch_bounds__(256) void k_softmax(float* __restrict__ enw, const float* __restrict__ ifert,
                                                 float* __restrict__ accum, float* __restrict__ roA,
                                                 const int* __restrict__ seqlen, int tstep) {
    int b = blockIdx.x, tid = threadIdx.x;
    __shared__ float redm[4], reds[4];
    int len = seqlen[b];
    float* row = enw + b * Tsz;
    float m = -INFINITY;
    for (int t = tid; t < len; t += 256) m = fmaxf(m, row[t]);
    for (int o = 32; o; o >>= 1) m = fmaxf(m, __shfl_xor(m, o, 64));
    if ((tid & 63) == 0) redm[tid >> 6] = m;
    __syncthreads();
    float M = fmaxf(fmaxf(redm[0], redm[1]), fmaxf(redm[2], redm[3]));
    float s = 0.f;
    for (int t = tid; t < len; t += 256) s += __expf(row[t] - M);
    for (int o = 32; o; o >>= 1) s += __shfl_xor(s, o, 64);
    if ((tid & 63) == 0) reds[tid >> 6] = s;
    __syncthreads();
    float inv = 1.f / (reds[0] + reds[1] + reds[2] + reds[3]);
    for (int t = tid; t < Tsz; t += 256) {
        float w = (t < len) ? __expf(row[t] - M) * inv : 0.f;
        row[t] = w;
        accum[b * Tsz + t] += w * ifert[b * Tsz + t] * 0.5f;
    }
    for (int d = tid; d < ENC; d += 256) roA[(size_t)(b * Nsz + tstep) * KRO + HID + EMB + d] = 0.f;
}

// ---------------- context: ctx[b,:] = sum_t w[b,t] * enc[b,t,:], chunked + atomics ----------------
#define TCH 10
__global__ __launch_bounds__(256) void k_ctx(const float* __restrict__ enw, const float* __restrict__ enc,
                                             const int* __restrict__ seqlen, float* __restrict__ roA,
                                             int tstep) {
    int b = blockIdx.y;
    int tid = threadIdx.x;
    int len = seqlen[b];
    int t0 = blockIdx.x * (Tsz / TCH);
    int t1 = min(t0 + Tsz / TCH, len);
    if (t0 >= t1) return;
    float a0 = 0.f, a1 = 0.f;
    const float* w = enw + b * Tsz;
    for (int t = t0; t < t1; t++) {
        float wt = w[t];
        const float* er = enc + (size_t)(b * Tsz + t) * ENC;
        a0 += wt * er[tid];
        a1 += wt * er[tid + 256];
    }
    float* dst = roA + (size_t)(b * Nsz + tstep) * KRO + HID + EMB;
    atomicAdd(dst + tid, a0);
    atomicAdd(dst + tid + 256, a1);
}

// ---------------- final small outputs: h, c, att_ctx, accum ----------------
__global__ __launch_bounds__(256) void k_final(const float* __restrict__ roA, const float* __restrict__ cbuf,
                                               const float* __restrict__ accum, float* __restrict__ out) {
    int idx = blockIdx.x * 256 + threadIdx.x;
    const int base = Bsz * Nsz * VOCAB;  // 16,040,000
    const int OH = Bsz * HID, OC = Bsz * HID, OA = Bsz * ENC, OAC = Bsz * Tsz;
    if (idx < OH) {
        int b = idx / HID, j = idx % HID;
        out[base + idx] = roA[(size_t)(b * Nsz + Nsz - 1) * KRO + j];
        return;
    }
    idx -= OH;
    if (idx < OC) { out[base + OH + idx] = cbuf[idx]; return; }
    idx -= OC;
    if (idx < OA) {
        int b = idx / ENC, d = idx % ENC;
        out[base + OH + OC + idx] = roA[(size_t)(b * Nsz + Nsz - 1) * KRO + HID + EMB + d];
        return;
    }
    idx -= OA;
    if (idx < OAC) out[base + OH + OC + OA + idx] = accum[idx];
}

extern "C" void kernel_launch(void* const* d_in, const int* in_sizes, int n_in,
                              void* d_out, int out_size, void* d_ws, size_t ws_size,
                              hipStream_t stream) {
    const float* enc   = (const float*)d_in[0];
    const int* labels  = (const int*)d_in[1];
    const int* seqlen  = (const int*)d_in[2];
    const float* table = (const float*)d_in[3];
    const float* Wih   = (const float*)d_in[4];
    const float* Whh   = (const float*)d_in[5];
    const float* bih   = (const float*)d_in[6];
    const float* bhh   = (const float*)d_in[7];
    const float* Wsm   = (const float*)d_in[8];
    const float* Wenc  = (const float*)d_in[9];
    const float* benc  = (const float*)d_in[10];
    const float* vatt  = (const float*)d_in[11];
    const float* Wfert = (const float*)d_in[12];
    const float* Wfb   = (const float*)d_in[13];
    const float* Wro   = (const float*)d_in[14];
    const float* bro   = (const float*)d_in[15];
    const float* Wout  = (const float*)d_in[16];
    const float* bout  = (const float*)d_in[17];
    float* out = (float*)d_out;

    // workspace layout (floats); total ~20.75M floats = ~83 MB
    float* ws = (float*)d_ws;
    float* roA    = ws;                      // [B*N][KRO] = 1600*2176 (s | emb | ctx concat rows)
    float* cbuf   = roA + (size_t)1600 * KRO;        // B*HID
    float* encctx = cbuf + Bsz * HID;                // [B*T][ATT]
    float* ifert  = encctx + (size_t)Bsz * Tsz * ATT;  // B*T
    float* accum  = ifert + Bsz * Tsz;               // B*T
    float* enw    = accum + Bsz * Tsz;               // B*T (energies -> weights)
    float* st     = enw + Bsz * Tsz;                 // [B][ATT]
    float* rmx    = st + Bsz * ATT;                  // [B*N][512] maxout readout

    k_init<<<(Bsz * Tsz + 255) / 256, 256, 0, stream>>>(accum);
    k_embed<<<(Bsz * Nsz * EMB + 255) / 256, 256, 0, stream>>>(labels, table, roA);
    // enc_ctx = enc @ W_enc^T + b_enc : [16000,512]@[512,1024]
    sgemm_nt<0><<<dim3(ATT / BN, (Bsz * Tsz) / BM), 256, 0, stream>>>(enc, Wenc, benc, encctx,
                                                                     Bsz * Tsz, ATT, ENC, ATT);
    k_ifert<<<(Bsz * Tsz * 64 + 255) / 256, 256, 0, stream>>>(enc, Wfert, ifert);

    for (int t = 0; t < Nsz; t++) {
        k_gates<<<512, 256, 0, stream>>>(roA, cbuf, Wih, Whh, bih, bhh, t);
        k_s<<<256, 256, 0, stream>>>(roA, Wsm, st, t);
        k_energy<<<(Bsz * Tsz * 64) / 256, 256, 0, stream>>>(encctx, st, Wfb, vatt, accum, seqlen, enw);
        k_softmax<<<Bsz, 256, 0, stream>>>(enw, ifert, accum, roA, seqlen, t);
        k_ctx<<<dim3(TCH, Bsz), 256, 0, stream>>>(enw, enc, seqlen, roA, t);
    }

    // readout: [1600,2176]@[2176,1024] + bias -> maxout pairs -> rmx [1600,512]
    sgemm_nt<1><<<dim3(1024 / BN, 1600 / BM), 256, 0, stream>>>(roA, Wro, bro, rmx, 1600, 1024, KRO, 512);
    // logits: [1600,512]@[512,10025] + bias -> d_out
    sgemm_nt<0><<<dim3((VOCAB + BN - 1) / BN, 1600 / BM), 256, 0, stream>>>(rmx, Wout, bout, out,
                                                                           1600, VOCAB, 512, VOCAB);
    k_final<<<(Bsz * HID * 2 + Bsz * ENC + Bsz * Tsz + 255) / 256, 256, 0, stream>>>(roA, cbuf, accum, out);
}

// Round 2
// 7996.074 us; speedup vs baseline: 1.0234x; 1.0234x over previous
//
#include <hip/hip_runtime.h>
#include <math.h>

#define Bsz 16
#define Tsz 1000
#define Nsz 100
#define ENC 512
#define VOCAB 10025
#define EMB 640
#define HID 1024
#define ATT 1024
#define KX (EMB + ENC)          // 1152
#define KRO (HID + EMB + ENC)   // 2176

typedef short s16x8 __attribute__((ext_vector_type(8)));
typedef unsigned short u16x4 __attribute__((ext_vector_type(4)));
typedef float f32x4 __attribute__((ext_vector_type(4)));

__device__ __forceinline__ float4 ld4(const float* p) { return *reinterpret_cast<const float4*>(p); }
__device__ __forceinline__ float dot4(float4 a, float4 b) { return a.x*b.x + a.y*b.y + a.z*b.z + a.w*b.w; }
__device__ __forceinline__ float sigmoidf_(float x) { return 1.f / (1.f + __expf(-x)); }
__device__ __forceinline__ float ftanh_(float x) {
    x = fminf(15.f, fmaxf(-15.f, x));
    float e = __expf(2.f * x);
    return (e - 1.f) / (e + 1.f);
}
__device__ __forceinline__ unsigned short f2bf(float x) {
    union { float f; unsigned u; } v; v.f = x;
    unsigned r = v.u + 0x7fffu + ((v.u >> 16) & 1u);
    return (unsigned short)(r >> 16);
}
__device__ __forceinline__ float bf2f(unsigned short h) {
    union { float f; unsigned u; } v; v.u = ((unsigned)h) << 16;
    return v.f;
}

// ---------------- init: zero accum ----------------
__global__ __launch_bounds__(256) void k_init(float* accum) {
    int i = blockIdx.x * 256 + threadIdx.x;
    if (i < Bsz * Tsz) accum[i] = 0.f;
}

// ---------------- shifted embedding into roA[:, HID:HID+EMB] ----------------
__global__ __launch_bounds__(256) void k_embed(const int* __restrict__ labels,
                                               const float* __restrict__ table,
                                               float* __restrict__ roA) {
    int idx = blockIdx.x * 256 + threadIdx.x;
    if (idx >= Bsz * Nsz * EMB) return;
    int e = idx % EMB;
    int bn = idx / EMB;
    int n = bn % Nsz, b = bn / Nsz;
    float v = 0.f;
    if (n > 0) {
        int lab = labels[b * Nsz + n - 1];
        v = table[(size_t)lab * EMB + e];
    }
    roA[(size_t)bn * KRO + HID + e] = v;
}

// ======== MFMA split-bf16 GEMM: C = A[M,K] @ W[Nc,K]^T + bias ========
// fp32 accuracy via 3-term split: Ah*Wh + Al*Wh + Ah*Wl (Al*Wl ~ 2^-18 dropped).
// 128x128 tile, 4 waves (2x2 of 64x64), 16x16x32 bf16 MFMA, BK=32 fp32 k per chunk.
// MODE 0: C[m*ldC+n] = acc + bias[n].  MODE 1: maxout over col pairs -> C[m*ldC+n/2].
template <int MODE>
__global__ __launch_bounds__(256) void mfma_gemm(const float* __restrict__ A,
                                                 const float* __restrict__ W,
                                                 const float* __restrict__ bias,
                                                 float* __restrict__ C,
                                                 int M, int Nc, int K, int ldC) {
    __shared__ unsigned short Ah[128][40], Al[128][40], Wh[128][40], Wl[128][40];
    int tid = threadIdx.x;
    int lane = tid & 63;
    int wave = tid >> 6;
    int wm = (wave >> 1) * 64, wn = (wave & 1) * 64;
    int m0 = blockIdx.y * 128, n0 = blockIdx.x * 128;
    int lrow = tid >> 1;            // 0..127 (staging row)
    int lcol = (tid & 1) * 16;      // 0 / 16  (staging k-offset)
    bool aval = (m0 + lrow) < M;
    bool wval = (n0 + lrow) < Nc;
    const float* Arow = A + (size_t)(m0 + lrow) * K + lcol;
    const float* Wrow = W + (size_t)(n0 + lrow) * K + lcol;
    int frow = lane & 15, fk = (lane >> 4) * 8;

    f32x4 acc[4][4];
#pragma unroll
    for (int i = 0; i < 4; i++)
#pragma unroll
        for (int j = 0; j < 4; j++) acc[i][j] = (f32x4){0.f, 0.f, 0.f, 0.f};

    const float4 z4 = {0.f, 0.f, 0.f, 0.f};
    for (int k0 = 0; k0 < K; k0 += 32) {
#pragma unroll
        for (int c = 0; c < 16; c += 4) {
            float4 av = aval ? ld4(Arow + k0 + c) : z4;
            u16x4 hv, lv;
            hv.x = f2bf(av.x); lv.x = f2bf(av.x - bf2f(hv.x));
            hv.y = f2bf(av.y); lv.y = f2bf(av.y - bf2f(hv.y));
            hv.z = f2bf(av.z); lv.z = f2bf(av.z - bf2f(hv.z));
            hv.w = f2bf(av.w); lv.w = f2bf(av.w - bf2f(hv.w));
            *(u16x4*)&Ah[lrow][lcol + c] = hv;
            *(u16x4*)&Al[lrow][lcol + c] = lv;
            float4 wv = wval ? ld4(Wrow + k0 + c) : z4;
            hv.x = f2bf(wv.x); lv.x = f2bf(wv.x - bf2f(hv.x));
            hv.y = f2bf(wv.y); lv.y = f2bf(wv.y - bf2f(hv.y));
            hv.z = f2bf(wv.z); lv.z = f2bf(wv.z - bf2f(hv.z));
            hv.w = f2bf(wv.w); lv.w = f2bf(wv.w - bf2f(hv.w));
            *(u16x4*)&Wh[lrow][lcol + c] = hv;
            *(u16x4*)&Wl[lrow][lcol + c] = lv;
        }
        __syncthreads();
        s16x8 afh[4], afl[4], bfh[4], bfl[4];
#pragma unroll
        for (int i = 0; i < 4; i++) {
            afh[i] = *(const s16x8*)&Ah[wm + i * 16 + frow][fk];
            afl[i] = *(const s16x8*)&Al[wm + i * 16 + frow][fk];
            bfh[i] = *(const s16x8*)&Wh[wn + i * 16 + frow][fk];
            bfl[i] = *(const s16x8*)&Wl[wn + i * 16 + frow][fk];
        }
#pragma unroll
        for (int mi = 0; mi < 4; mi++)
#pragma unroll
            for (int ni = 0; ni < 4; ni++) {
                acc[mi][ni] = __builtin_amdgcn_mfma_f32_16x16x32_bf16(afh[mi], bfh[ni], acc[mi][ni], 0, 0, 0);
                acc[mi][ni] = __builtin_amdgcn_mfma_f32_16x16x32_bf16(afl[mi], bfh[ni], acc[mi][ni], 0, 0, 0);
                acc[mi][ni] = __builtin_amdgcn_mfma_f32_16x16x32_bf16(afh[mi], bfl[ni], acc[mi][ni], 0, 0, 0);
            }
        __syncthreads();
    }
    // epilogue: C/D layout col = lane&15, row = (lane>>4)*4 + r
    int crb = (lane >> 4) * 4;
    int ccol = lane & 15;
#pragma unroll
    for (int mi = 0; mi < 4; mi++) {
#pragma unroll
        for (int r = 0; r < 4; r++) {
            int m = m0 + wm + mi * 16 + crb + r;
#pragma unroll
            for (int ni = 0; ni < 4; ni++) {
                int n = n0 + wn + ni * 16 + ccol;
                if (MODE == 0) {
                    if (m < M && n < Nc) C[(size_t)m * ldC + n] = acc[mi][ni][r] + bias[n];
                } else {
                    float v = (n < Nc) ? acc[mi][ni][r] + bias[n] : -INFINITY;
                    float o = __shfl_xor(v, 1, 64);
                    if (((lane & 1) == 0) && m < M && n < Nc)
                        C[(size_t)m * ldC + (n >> 1)] = fmaxf(v, o);
                }
            }
        }
    }
}

// ---------------- inv_fertility: sigmoid(enc @ W_fert), one wave per (b,t) ----------------
__global__ __launch_bounds__(256) void k_ifert(const float* __restrict__ enc,
                                               const float* __restrict__ Wfert,
                                               float* __restrict__ ifert) {
    int wv = (blockIdx.x * 256 + threadIdx.x) >> 6;
    int lane = threadIdx.x & 63;
    if (wv >= Bsz * Tsz) return;
    const float* row = enc + (size_t)wv * ENC;
    float s = 0.f;
    for (int k = lane * 4; k < ENC; k += 256) s += dot4(ld4(row + k), ld4(Wfert + k));
    for (int o = 32; o; o >>= 1) s += __shfl_xor(s, o, 64);
    if (lane == 0) ifert[wv] = 1.f / (1.f + __expf(-s));
}

// ---------------- gates + LSTM cell: one wave per (hid unit j, batch-half) ----------------
__global__ __launch_bounds__(256) void k_gates(float* __restrict__ roA, float* __restrict__ cbuf,
                                               const float* __restrict__ Wih, const float* __restrict__ Whh,
                                               const float* __restrict__ bih, const float* __restrict__ bhh,
                                               int t) {
    int wv = (blockIdx.x * 256 + threadIdx.x) >> 6;  // 0..2047
    int lane = threadIdx.x & 63;
    int j = wv >> 1;
    int b0 = (wv & 1) << 3;
    float acc[4][8];
#pragma unroll
    for (int g = 0; g < 4; g++)
#pragma unroll
        for (int bb = 0; bb < 8; bb++) acc[g][bb] = 0.f;

    const float* wi0 = Wih + (size_t)(0 * HID + j) * KX;
    const float* wi1 = Wih + (size_t)(1 * HID + j) * KX;
    const float* wi2 = Wih + (size_t)(2 * HID + j) * KX;
    const float* wi3 = Wih + (size_t)(3 * HID + j) * KX;
    const float* wh0 = Whh + (size_t)(0 * HID + j) * HID;
    const float* wh1 = Whh + (size_t)(1 * HID + j) * HID;
    const float* wh2 = Whh + (size_t)(2 * HID + j) * HID;
    const float* wh3 = Whh + (size_t)(3 * HID + j) * HID;
    const float* xrow[8];
    const float* prow[8];
#pragma unroll
    for (int bb = 0; bb < 8; bb++) {
        xrow[bb] = roA + (size_t)((b0 + bb) * Nsz + t) * KRO;
        prow[bb] = roA + (size_t)((b0 + bb) * Nsz + (t - 1)) * KRO;
    }
    for (int k = lane * 4; k < EMB; k += 256) {
        float4 w0 = ld4(wi0 + k), w1 = ld4(wi1 + k), w2 = ld4(wi2 + k), w3 = ld4(wi3 + k);
#pragma unroll
        for (int bb = 0; bb < 8; bb++) {
            float4 x = ld4(xrow[bb] + HID + k);
            acc[0][bb] += dot4(w0, x); acc[1][bb] += dot4(w1, x);
            acc[2][bb] += dot4(w2, x); acc[3][bb] += dot4(w3, x);
        }
    }
    if (t > 0) {
        for (int k = lane * 4; k < ENC; k += 256) {
            float4 w0 = ld4(wi0 + EMB + k), w1 = ld4(wi1 + EMB + k), w2 = ld4(wi2 + EMB + k), w3 = ld4(wi3 + EMB + k);
#pragma unroll
            for (int bb = 0; bb < 8; bb++) {
                float4 x = ld4(prow[bb] + HID + EMB + k);
                acc[0][bb] += dot4(w0, x); acc[1][bb] += dot4(w1, x);
                acc[2][bb] += dot4(w2, x); acc[3][bb] += dot4(w3, x);
            }
        }
        for (int k = lane * 4; k < HID; k += 256) {
            float4 w0 = ld4(wh0 + k), w1 = ld4(wh1 + k), w2 = ld4(wh2 + k), w3 = ld4(wh3 + k);
#pragma unroll
            for (int bb = 0; bb < 8; bb++) {
                float4 x = ld4(prow[bb] + k);
                acc[0][bb] += dot4(w0, x); acc[1][bb] += dot4(w1, x);
                acc[2][bb] += dot4(w2, x); acc[3][bb] += dot4(w3, x);
            }
        }
    }
#pragma unroll
    for (int g = 0; g < 4; g++)
#pragma unroll
        for (int bb = 0; bb < 8; bb++) {
            float v = acc[g][bb];
            for (int o = 32; o; o >>= 1) v += __shfl_xor(v, o, 64);
            acc[g][bb] = v;
        }
    if (lane < 8) {
        int b = b0 + lane;
        float gi = acc[0][lane] + bih[j] + bhh[j];
        float gf = acc[1][lane] + bih[HID + j] + bhh[HID + j];
        float gg = acc[2][lane] + bih[2 * HID + j] + bhh[2 * HID + j];
        float go = acc[3][lane] + bih[3 * HID + j] + bhh[3 * HID + j];
        float cold = (t > 0) ? cbuf[b * HID + j] : 0.f;
        float cn = sigmoidf_(gf) * cold + sigmoidf_(gi) * ftanh_(gg);
        float hn = sigmoidf_(go) * ftanh_(cn);
        cbuf[b * HID + j] = cn;
        roA[(size_t)(b * Nsz + t) * KRO + j] = hn;
    }
}

// ---------------- s_t = h_new @ W_s^T : one wave per attention unit a ----------------
__global__ __launch_bounds__(256) void k_s(const float* __restrict__ roA, const float* __restrict__ Wsm,
                                           float* __restrict__ st, int t) {
    int wv = (blockIdx.x * 256 + threadIdx.x) >> 6;  // 0..1023 = a
    int lane = threadIdx.x & 63;
    float acc[16];
#pragma unroll
    for (int b = 0; b < 16; b++) acc[b] = 0.f;
    const float* wr = Wsm + (size_t)wv * HID;
    const float* hrow[16];
#pragma unroll
    for (int b = 0; b < 16; b++) hrow[b] = roA + (size_t)(b * Nsz + t) * KRO;
    for (int k = lane * 4; k < HID; k += 256) {
        float4 w = ld4(wr + k);
#pragma unroll
        for (int b = 0; b < 16; b++) acc[b] += dot4(w, ld4(hrow[b] + k));
    }
#pragma unroll
    for (int b = 0; b < 16; b++) {
        float v = acc[b];
        for (int o = 32; o; o >>= 1) v += __shfl_xor(v, o, 64);
        acc[b] = v;
    }
    if (lane < 16) st[lane * ATT + wv] = acc[lane];
}

// ---------------- attention energies: one wave per (b,t) ----------------
__global__ __launch_bounds__(256) void k_energy(const float* __restrict__ encctx,
                                                const float* __restrict__ st,
                                                const float* __restrict__ Wfb,
                                                const float* __restrict__ vatt,
                                                const float* __restrict__ accum,
                                                const int* __restrict__ seqlen,
                                                float* __restrict__ enw) {
    int wv = (blockIdx.x * 256 + threadIdx.x) >> 6;  // 0..15999
    int lane = threadIdx.x & 63;
    int b = wv / Tsz, t = wv - b * Tsz;
    if (t >= seqlen[b]) {
        if (lane == 0) enw[wv] = -INFINITY;
        return;
    }
    float ac = accum[wv];
    const float* ec = encctx + (size_t)wv * ATT;
    const float* sr = st + b * ATT;
    float e = 0.f;
    for (int k = lane * 4; k < ATT; k += 256) {
        float4 c4 = ld4(ec + k), s4 = ld4(sr + k), f4 = ld4(Wfb + k), v4 = ld4(vatt + k);
        e += ftanh_(c4.x + s4.x + ac * f4.x) * v4.x;
        e += ftanh_(c4.y + s4.y + ac * f4.y) * v4.y;
        e += ftanh_(c4.z + s4.z + ac * f4.z) * v4.z;
        e += ftanh_(c4.w + s4.w + ac * f4.w) * v4.w;
    }
    for (int o = 32; o; o >>= 1) e += __shfl_xor(e, o, 64);
    if (lane == 0) enw[wv] = e;
}

// ---------------- softmax + accum update + zero ctx slot: one block per b ----------------
__global__ __launch_bounds__(256) void k_softmax(float* __restrict__ enw, const float* __restrict__ ifert,
                                                 float* __restrict__ accum, float* __restrict__ roA,
                                                 const int* __restrict__ seqlen, int tstep) {
    int b = blockIdx.x, tid = threadIdx.x;
    __shared__ float redm[4], reds[4];
    int len = seqlen[b];
    float* row = enw + b * Tsz;
    float m = -INFINITY;
    for (int t = tid; t < len; t += 256) m = fmaxf(m, row[t]);
    for (int o = 32; o; o >>= 1) m = fmaxf(m, __shfl_xor(m, o, 64));
    if ((tid & 63) == 0) redm[tid >> 6] = m;
    __syncthreads();
    float M = fmaxf(fmaxf(redm[0], redm[1]), fmaxf(redm[2], redm[3]));
    float s = 0.f;
    for (int t = tid; t < len; t += 256) s += __expf(row[t] - M);
    for (int o = 32; o; o >>= 1) s += __shfl_xor(s, o, 64);
    if ((tid & 63) == 0) reds[tid >> 6] = s;
    __syncthreads();
    float inv = 1.f / (reds[0] + reds[1] + reds[2] + reds[3]);
    for (int t = tid; t < Tsz; t += 256) {
        float w = (t < len) ? __expf(row[t] - M) * inv : 0.f;
        row[t] = w;
        accum[b * Tsz + t] += w * ifert[b * Tsz + t] * 0.5f;
    }
    for (int d = tid; d < ENC; d += 256) roA[(size_t)(b * Nsz + tstep) * KRO + HID + EMB + d] = 0.f;
}

// ---------------- context: ctx[b,:] = sum_t w[b,t] * enc[b,t,:], chunked + atomics ----------------
#define TCH 10
__global__ __launch_bounds__(256) void k_ctx(const float* __restrict__ enw, const float* __restrict__ enc,
                                             const int* __restrict__ seqlen, float* __restrict__ roA,
                                             int tstep) {
    int b = blockIdx.y;
    int tid = threadIdx.x;
    int len = seqlen[b];
    int t0 = blockIdx.x * (Tsz / TCH);
    int t1 = min(t0 + Tsz / TCH, len);
    if (t0 >= t1) return;
    float a0 = 0.f, a1 = 0.f;
    const float* w = enw + b * Tsz;
    for (int t = t0; t < t1; t++) {
        float wt = w[t];
        const float* er = enc + (size_t)(b * Tsz + t) * ENC;
        a0 += wt * er[tid];
        a1 += wt * er[tid + 256];
    }
    float* dst = roA + (size_t)(b * Nsz + tstep) * KRO + HID + EMB;
    atomicAdd(dst + tid, a0);
    atomicAdd(dst + tid + 256, a1);
}

// ---------------- final small outputs: h, c, att_ctx, accum ----------------
__global__ __launch_bounds__(256) void k_final(const float* __restrict__ roA, const float* __restrict__ cbuf,
                                               const float* __restrict__ accum, float* __restrict__ out) {
    int idx = blockIdx.x * 256 + threadIdx.x;
    const int base = Bsz * Nsz * VOCAB;  // 16,040,000
    const int OH = Bsz * HID, OC = Bsz * HID, OA = Bsz * ENC, OAC = Bsz * Tsz;
    if (idx < OH) {
        int b = idx / HID, j = idx % HID;
        out[base + idx] = roA[(size_t)(b * Nsz + Nsz - 1) * KRO + j];
        return;
    }
    idx -= OH;
    if (idx < OC) { out[base + OH + idx] = cbuf[idx]; return; }
    idx -= OC;
    if (idx < OA) {
        int b = idx / ENC, d = idx % ENC;
        out[base + OH + OC + idx] = roA[(size_t)(b * Nsz + Nsz - 1) * KRO + HID + EMB + d];
        return;
    }
    idx -= OA;
    if (idx < OAC) out[base + OH + OC + OA + idx] = accum[idx];
}

extern "C" void kernel_launch(void* const* d_in, const int* in_sizes, int n_in,
                              void* d_out, int out_size, void* d_ws, size_t ws_size,
                              hipStream_t stream) {
    const float* enc   = (const float*)d_in[0];
    const int* labels  = (const int*)d_in[1];
    const int* seqlen  = (const int*)d_in[2];
    const float* table = (const float*)d_in[3];
    const float* Wih   = (const float*)d_in[4];
    const float* Whh   = (const float*)d_in[5];
    const float* bih   = (const float*)d_in[6];
    const float* bhh   = (const float*)d_in[7];
    const float* Wsm   = (const float*)d_in[8];
    const float* Wenc  = (const float*)d_in[9];
    const float* benc  = (const float*)d_in[10];
    const float* vatt  = (const float*)d_in[11];
    const float* Wfert = (const float*)d_in[12];
    const float* Wfb   = (const float*)d_in[13];
    const float* Wro   = (const float*)d_in[14];
    const float* bro   = (const float*)d_in[15];
    const float* Wout  = (const float*)d_in[16];
    const float* bout  = (const float*)d_in[17];
    float* out = (float*)d_out;

    // workspace layout (floats); total ~20.75M floats = ~83 MB
    float* ws = (float*)d_ws;
    float* roA    = ws;                              // [B*N][KRO]
    float* cbuf   = roA + (size_t)1600 * KRO;        // B*HID
    float* encctx = cbuf + Bsz * HID;                // [B*T][ATT]
    float* ifert  = encctx + (size_t)Bsz * Tsz * ATT;
    float* accum  = ifert + Bsz * Tsz;
    float* enw    = accum + Bsz * Tsz;
    float* st     = enw + Bsz * Tsz;
    float* rmx    = st + Bsz * ATT;                  // [B*N][512]

    k_init<<<(Bsz * Tsz + 255) / 256, 256, 0, stream>>>(accum);
    k_embed<<<(Bsz * Nsz * EMB + 255) / 256, 256, 0, stream>>>(labels, table, roA);
    // enc_ctx = enc @ W_enc^T + b_enc : [16000,512]@[512,1024]
    mfma_gemm<0><<<dim3(ATT / 128, (Bsz * Tsz) / 128), 256, 0, stream>>>(enc, Wenc, benc, encctx,
                                                                        Bsz * Tsz, ATT, ENC, ATT);
    k_ifert<<<(Bsz * Tsz * 64 + 255) / 256, 256, 0, stream>>>(enc, Wfert, ifert);

    for (int t = 0; t < Nsz; t++) {
        k_gates<<<512, 256, 0, stream>>>(roA, cbuf, Wih, Whh, bih, bhh, t);
        k_s<<<256, 256, 0, stream>>>(roA, Wsm, st, t);
        k_energy<<<(Bsz * Tsz * 64) / 256, 256, 0, stream>>>(encctx, st, Wfb, vatt, accum, seqlen, enw);
        k_softmax<<<Bsz, 256, 0, stream>>>(enw, ifert, accum, roA, seqlen, t);
        k_ctx<<<dim3(TCH, Bsz), 256, 0, stream>>>(enw, enc, seqlen, roA, t);
    }

    // readout: [1600,2176]@[2176,1024] + bias -> maxout -> rmx [1600,512]
    mfma_gemm<1><<<dim3(1024 / 128, (1600 + 127) / 128), 256, 0, stream>>>(roA, Wro, bro, rmx,
                                                                          1600, 1024, KRO, 512);
    // logits: [1600,512]@[512,10025] + bias -> d_out
    mfma_gemm<0><<<dim3((VOCAB + 127) / 128, (1600 + 127) / 128), 256, 0, stream>>>(rmx, Wout, bout, out,
                                                                                   1600, VOCAB, 512, VOCAB);
    k_final<<<(Bsz * HID * 2 + Bsz * ENC + Bsz * Tsz + 255) / 256, 256, 0, stream>>>(roA, cbuf, accum, out);
}